// Round 7
// baseline (640.766 us; speedup 1.0000x reference)
//
#include <hip/hip_runtime.h>
#include <math.h>

#define B_ 128
#define T_ 256
#define N_ 16
#define K_ 10
#define H_ 20
#define TN_ 4096     // T_*N_
#define NTQ_ 128     // t-pairs per k

#define REP20(F) F(0) F(1) F(2) F(3) F(4) F(5) F(6) F(7) F(8) F(9) \
                 F(10) F(11) F(12) F(13) F(14) F(15) F(16) F(17) F(18) F(19)

__device__ __forceinline__ float wsum(float v)
{
#pragma unroll
    for (int off = 32; off; off >>= 1) v += __shfl_xor(v, off);
    return v;
}

// ---------------------------------------------------------------------------
// ONE fused kernel, 2 graph nodes total (6KB memset + this).
// Block = (kn = k*16+n, tq = t-pair). 256 thr; thread -> (tt=tq*2+half, b).
//  - x standardized over b in-block (ddof=1, no eps), cross-wave via LDS red
//  - straight-line MLP, block-uniform weights on the scalar (s_load) pipe
//  - KEY EXPERIMENT: amdgpu_waves_per_eu(2,4) raises the allocator's VGPR
//    budget to 128-256 so h0..h19/g0..g19 stay in ArchVGPRs. Every prior
//    variant reported VGPR_Count 24-88 with ~40 live floats and no scratch
//    traffic => AGPR shuffling, a constant ~2.2x VALU bloat (~100us busy-time
//    in R1-R6 regardless of codegen).
//  - t standardized over b (ddof=1, std+1e-8); z -> ws (coalesced)
//  - ticket per (k,tq): 16th n-block computes products; penalty = pj^2
//    (product of 16 marginal means underflows to 0 in fp32 ref; R2-R6 pass);
//    winner stores partial (plain store), last of 1280 winners sums partials
//    and writes out. No float atomics -> only tickets/done need memset.
// ---------------------------------------------------------------------------
__global__ __launch_bounds__(256) __attribute__((amdgpu_waves_per_eu(2, 4)))
void k_fused(
    const float* __restrict__ x,
    const float* __restrict__ W1, const float* __restrict__ b1,
    const float* __restrict__ W2, const float* __restrict__ b2,
    const float* __restrict__ W3, const float* __restrict__ b3,
    float* __restrict__ out,
    unsigned int* __restrict__ tickets,   // ws: 1280 u32, zeroed
    unsigned int* __restrict__ done,      // ws: 1 u32, zeroed
    float* __restrict__ partials,         // ws: 1280 f32 (no init needed)
    float* __restrict__ zbuf)             // ws: [K][T][N][B] f32
{
    __shared__ float red[4], red2[4], pjsq[2];
    __shared__ int   flag, flag2;

    const int tq   = blockIdx.x;         // 0..127
    const int kn   = blockIdx.y;         // 0..159
    const int k    = kn >> 4;
    const int n    = kn & 15;
    const int tid  = threadIdx.x;
    const int wv   = tid >> 6;
    const int l    = tid & 63;
    const int half = tid >> 7;           // which t of the pair
    const int hb   = half * 2;
    const int tt   = tq * 2 + half;
    const int b    = tid & 127;

    // ---- x gather (L2-cached) + standardize over b (ddof=1, no eps) ----
    const float xv = x[b * TN_ + tt * N_ + n];
    { const float s = wsum(xv); if (l == 0) red[wv] = s; }
    __syncthreads();
    const float xmu = (red[hb] + red[hb + 1]) * (1.f / 128.f);
    const float xd  = xv - xmu;
    { const float s = wsum(xd * xd); if (l == 0) red2[wv] = s; }
    __syncthreads();
    const float u = xd * __builtin_amdgcn_rsqf((red2[hb] + red2[hb + 1]) * (1.f / 127.f));

    // ---- block-uniform weight bases -> scalar pipe ----
    const float* __restrict__ w1c = W1 + kn * H_;
    const float* __restrict__ b1c = b1 + kn * H_;
    const float* __restrict__ w2c = W2 + kn * H_ * H_;
    const float* __restrict__ b2c = b2 + kn * H_;
    const float* __restrict__ w3c = W3 + kn * H_;
    const float  bb3 = b3[kn];
    float w3sum = 0.f;                   // uniform -> SALU
#define W3S(i) w3sum += w3c[i];
    REP20(W3S)

    // ---- Layer 1 + ReLU ----
#define DECLH(i) float h##i;
    REP20(DECLH)
    float s1 = 0.f;
#define L1(i) h##i = fmaxf(fmaf(u, w1c[i], b1c[i]), 0.f); s1 += h##i;
    REP20(L1)

    // ---- LayerNorm 1 (biased var, eps 1e-5) ----
    const float mu1 = s1 * 0.05f;
    float v1 = 0.f;
#define VAR1(i) { const float d = h##i - mu1; v1 = fmaf(d, d, v1); }
    REP20(VAR1)
    const float r1 = __builtin_amdgcn_rsqf(v1 * 0.05f + 1e-5f);
    const float m1 = mu1 * r1;
#define NRM1(i) h##i = fmaf(h##i, r1, -m1);
    REP20(NRM1)

    // ---- Layer 2 (20x20) + ReLU, even/odd dual chains ----
#define DECLG(i) float g##i;
    REP20(DECLG)
    float s2 = 0.f;
#define L2E(o,i) ae = fmaf(h##i, w2c[(o) * 20 + (i)], ae);
#define L2O(o,i) ao = fmaf(h##i, w2c[(o) * 20 + (i)], ao);
#define L2ROW(o) { float ae = b2c[o], ao = 0.f; \
    L2E(o,0) L2O(o,1) L2E(o,2) L2O(o,3) L2E(o,4) L2O(o,5) L2E(o,6) L2O(o,7) \
    L2E(o,8) L2O(o,9) L2E(o,10) L2O(o,11) L2E(o,12) L2O(o,13) L2E(o,14) \
    L2O(o,15) L2E(o,16) L2O(o,17) L2E(o,18) L2O(o,19) \
    g##o = fmaxf(ae + ao, 0.f); s2 += g##o; }
    REP20(L2ROW)

    // ---- LayerNorm 2 folded into layer-3 dot ----
    const float mu2 = s2 * 0.05f;
    float v2 = 0.f;
#define VAR2(i) { const float d = g##i - mu2; v2 = fmaf(d, d, v2); }
    REP20(VAR2)
    const float r2 = __builtin_amdgcn_rsqf(v2 * 0.05f + 1e-5f);
    const float m2 = mu2 * r2;

    float de = 0.f, dq = 0.f;
#define L3E(i) de = fmaf(g##i, w3c[i], de);
#define L3O(i) dq = fmaf(g##i, w3c[i], dq);
    L3E(0) L3O(1) L3E(2) L3O(3) L3E(4) L3O(5) L3E(6) L3O(7) L3E(8) L3O(9)
    L3E(10) L3O(11) L3E(12) L3O(13) L3E(14) L3O(15) L3E(16) L3O(17) L3E(18) L3O(19)
    // t = r2*dot - m2*w3sum + b3
    const float tv = fmaf(r2, de + dq, fmaf(-m2, w3sum, bb3));

    // ---- standardize t over b (ddof=1, std+1e-8) ----
    __syncthreads();
    { const float s = wsum(tv); if (l == 0) red[wv] = s; }
    __syncthreads();
    const float tmu = (red[hb] + red[hb + 1]) * (1.f / 128.f);
    const float e   = tv - tmu;
    { const float s = wsum(e * e); if (l == 0) red2[wv] = s; }
    __syncthreads();
    const float sd = sqrtf((red2[hb] + red2[hb + 1]) * (1.f / 127.f));
    const float z  = e * (1.f / (sd + 1e-8f));

    zbuf[(((size_t)k * T_ + tt) * N_ + n) * B_ + b] = z;

    // ---- ticket: last of the 16 n-blocks for (k,tq) does the products ----
    __syncthreads();                     // drains stores
    if (tid == 0) {
        __threadfence();                 // release
        flag = (atomicAdd(&tickets[k * NTQ_ + tq], 1u) == 15u);
    }
    __syncthreads();
    if (!flag) return;
    __threadfence();                     // acquire (all threads)
    __syncthreads();

    // ---- product over n per (tt,b); partial = (pj0^2+pj1^2)/2560 ----
    const float* __restrict__ zr = zbuf + ((size_t)k * T_ + tt) * (N_ * B_);
    float p = zr[b];
#pragma unroll
    for (int nn = 1; nn < N_; ++nn) p *= zr[nn * B_ + b];
    { const float s = wsum(p); if (l == 0) red[wv] = s; }
    __syncthreads();
    if ((tid & 127) == 0) {
        const float pj = (red[hb] + red[hb + 1]) * (1.f / 128.f);
        pjsq[half] = pj * pj;
    }
    __syncthreads();
    if (tid == 0) {
        partials[k * NTQ_ + tq] = (pjsq[0] + pjsq[1]) * (1.f / (K_ * T_));
        __threadfence();                 // partial visible before done-add
        flag2 = (atomicAdd(done, 1u) == (K_ * NTQ_ - 1u));
    }
    __syncthreads();
    if (!flag2) return;
    __threadfence();                     // acquire before reading partials
    __syncthreads();

    // ---- final: one wave sums the 1280 partials, writes out ----
    if (tid < 64) {
        float a = 0.f;
#pragma unroll
        for (int j = 0; j < 20; ++j) a += partials[j * 64 + tid];
        a = wsum(a);
        if (tid == 0) out[0] = a;
    }
}

// ---------------------------------------------------------------------------
extern "C" void kernel_launch(void* const* d_in, const int* in_sizes, int n_in,
                              void* d_out, int out_size, void* d_ws, size_t ws_size,
                              hipStream_t stream)
{
    const float* x  = (const float*)d_in[0];
    const float* W1 = (const float*)d_in[1];
    const float* b1 = (const float*)d_in[2];
    const float* W2 = (const float*)d_in[3];
    const float* b2 = (const float*)d_in[4];
    const float* W3 = (const float*)d_in[5];
    const float* b3 = (const float*)d_in[6];
    float* out = (float*)d_out;

    char* ws = (char*)d_ws;
    unsigned int* tickets  = (unsigned int*)ws;            // 1280 u32 (5120 B)
    unsigned int* done     = (unsigned int*)(ws + 5120);   // 1 u32
    float*        partials = (float*)(ws + 8192);          // 1280 f32
    float*        zbuf     = (float*)(ws + 16384);         // 20 MB [K][T][N][B]

    hipMemsetAsync(ws, 0, 6144, stream);                   // tickets + done

    dim3 grid(NTQ_, K_ * N_);                              // 128 x 160
    k_fused<<<grid, 256, 0, stream>>>(x, W1, b1, W2, b2, W3, b3,
                                      out, tickets, done, partials, zbuf);
}

// Round 8
// 273.866 us; speedup vs baseline: 2.3397x; 2.3397x over previous
//
#include <hip/hip_runtime.h>
#include <math.h>

#define B_ 128
#define T_ 256
#define N_ 16
#define K_ 10
#define H_ 20
#define TN_ 4096     // T_*N_
#define S_ 32768     // samples per (k,n)

typedef __attribute__((ext_vector_type(8))) short bf16x8;
typedef __attribute__((ext_vector_type(4))) float f32x4;

union U4B { uint4 u; bf16x8 b; };

#define REP20(F) F(0) F(1) F(2) F(3) F(4) F(5) F(6) F(7) F(8) F(9) \
                 F(10) F(11) F(12) F(13) F(14) F(15) F(16) F(17) F(18) F(19)
#define REP16(F) F(0) F(1) F(2) F(3) F(4) F(5) F(6) F(7) F(8) F(9) \
                 F(10) F(11) F(12) F(13) F(14) F(15)

__device__ __forceinline__ float wsum(float v)
{
#pragma unroll
    for (int off = 32; off; off >>= 1) v += __shfl_xor(v, off);
    return v;
}

// Split (a,b) into packed truncated-bf16 "hi" and packed truncated-bf16 of the
// exact residual "lo". Pure bit-ops: no cvt rounding-mode or pack-order
// assumptions. a occupies low 16 bits, b high 16 bits -- consistently for A
// and B operands, so any HW k-permutation cancels in the MFMA dot product.
__device__ __forceinline__ void split2(float a, float b, unsigned& hi, unsigned& lo)
{
    const unsigned au = __float_as_uint(a), bu = __float_as_uint(b);
    hi = (au >> 16) | (bu & 0xffff0000u);
    const float ra = a - __uint_as_float(au & 0xffff0000u);   // exact
    const float rb = b - __uint_as_float(bu & 0xffff0000u);   // exact
    lo = (__float_as_uint(ra) >> 16) | (__float_as_uint(rb) & 0xffff0000u);
}

// ---------------------------------------------------------------------------
// Kernel 1: standardize inputs over batch dim B (ddof=1, no eps).
// One WAVE per (tt,n) column. x: [B][T][N]; xs2: [N][T][B]. (R2-proven.)
// ---------------------------------------------------------------------------
__global__ __launch_bounds__(256) void k_std(const float* __restrict__ x,
                                             float* __restrict__ xs2)
{
    const int wid = (blockIdx.x * 256 + threadIdx.x) >> 6;   // 0..4095 column
    const int l   = threadIdx.x & 63;
    const int tt  = wid >> 4;
    const int n   = wid & 15;

    const float a0 = x[l * TN_ + wid];
    const float a1 = x[(64 + l) * TN_ + wid];

    const float mu = wsum(a0 + a1) * (1.f / 128.f);
    const float d0 = a0 - mu, d1 = a1 - mu;
    const float r  = __builtin_amdgcn_rsqf(wsum(fmaf(d0, d0, d1 * d1)) * (1.f / 127.f));

    float* col = xs2 + ((size_t)n * T_ + tt) * B_;
    col[l]      = d0 * r;
    col[64 + l] = d1 * r;
}

// ---------------------------------------------------------------------------
// Kernel 2: MLP. Block = (kn, 256-sample chunk), 4 waves.
//  - L1 + LN1 scalar per-thread (uniform s_load weights, R3-proven path)
//  - pack h-hat into bf16 hi/lo, stage in LDS rows of 28 u32
//    (hi slots 0-9, pad 10-11, lo slots 12-21, pad 22-27; 16B-aligned reads)
//  - per wave, 4 MFMA passes of 16 samples: D[16 samp][32 neurons] via
//    2 N-tiles x 3 split products of mfma_f32_16x16x32_bf16 (K=20 padded
//    to 32; lane-groups 2,3 masked to zero in the A fragment)
//  - LN2+L3 folded: 16-lane shuffle reductions of (Sum g, Sum g^2, Sum g*w3)
//  - store t to tb [K][T][N][B]
// ---------------------------------------------------------------------------
__global__ __launch_bounds__(256) void k_mlp(
    const float* __restrict__ xs2,
    const float* __restrict__ W1, const float* __restrict__ b1,
    const float* __restrict__ W2, const float* __restrict__ b2,
    const float* __restrict__ W3, const float* __restrict__ b3,
    float* __restrict__ tb)
{
    __shared__ unsigned hs[256 * 28];   // per-sample packed h-hat
    __shared__ unsigned wB[32 * 28];    // W2 as B operand (rows=out neuron)
    __shared__ float sb2[32], sw3[32];

    const int kn  = blockIdx.y;         // k*16+n
    const int k   = kn >> 4;
    const int n   = kn & 15;
    const int tid = threadIdx.x;
    const int w   = tid >> 6;
    const int L   = tid & 63;
    const int g   = L >> 4;             // k-block group
    const int r16 = L & 15;
    const int q0b = blockIdx.x * 256;

    // ---- stage W2 -> split bf16 in wB ----
    const float* __restrict__ w2c = W2 + kn * 400;
    for (int j = tid; j < 320; j += 256) {          // 32 rows x 10 k-pairs
        const int o = j / 10, kp = j % 10;
        unsigned hi = 0u, lo = 0u;
        if (o < 20)
            split2(w2c[o * 20 + 2 * kp], w2c[o * 20 + 2 * kp + 1], hi, lo);
        wB[o * 28 + kp]      = hi;
        wB[o * 28 + 12 + kp] = lo;
    }
    if (tid < 128) {                                // zero pad slots 10,11,22,23
        const int o = tid >> 2, c = tid & 3;
        wB[o * 28 + ((c < 2) ? 10 + c : 20 + c)] = 0u;
    }
    if (tid < 32) {
        sb2[tid] = (tid < 20) ? b2[kn * 20 + tid] : 0.f;
        sw3[tid] = (tid < 20) ? W3[kn * 20 + tid] : 0.f;
    }

    // ---- uniform scalars ----
    const float* __restrict__ w1c = W1 + kn * H_;
    const float* __restrict__ b1c = b1 + kn * H_;
    const float* __restrict__ w3c = W3 + kn * H_;
    const float  bb3 = b3[kn];
    float w3sum = 0.f;
#define W3S(i) w3sum += w3c[i];
    REP20(W3S)

    // ---- L1 + LN1 (scalar, R3-proven math) ----
    const float u = xs2[n * S_ + q0b + tid];
#define DECLH(i) float h##i;
    REP20(DECLH)
    float s1 = 0.f;
#define L1(i) h##i = fmaxf(fmaf(u, w1c[i], b1c[i]), 0.f); s1 += h##i;
    REP20(L1)
    const float mu1 = s1 * 0.05f;
    float v1 = 0.f;
#define VAR1(i) { const float d = h##i - mu1; v1 = fmaf(d, d, v1); }
    REP20(VAR1)
    const float r1 = __builtin_amdgcn_rsqf(v1 * 0.05f + 1e-5f);
    const float m1 = mu1 * r1;
#define NRM1(i) h##i = fmaf(h##i, r1, -m1);
    REP20(NRM1)

    // ---- pack h-hat, write own LDS row ----
    {
        unsigned* row = hs + tid * 28;
        unsigned hi, lo;
#define PKW(m, i0, i1) split2(h##i0, h##i1, hi, lo); row[m] = hi; row[12 + m] = lo;
        PKW(0, 0, 1) PKW(1, 2, 3) PKW(2, 4, 5) PKW(3, 6, 7) PKW(4, 8, 9)
        PKW(5, 10, 11) PKW(6, 12, 13) PKW(7, 14, 15) PKW(8, 16, 17) PKW(9, 18, 19)
        *reinterpret_cast<uint2*>(row + 10) = make_uint2(0u, 0u);
        *reinterpret_cast<uint2*>(row + 22) = make_uint2(0u, 0u);
    }
    __syncthreads();

    // ---- per-lane hoists ----
    const int slhi = (g < 2) ? g * 4 : 8;     // groups 2,3 clamp; masked below
    const int sllo = 12 + slhi;
    U4B bh0, bl0, bh1, bl1;
    bh0.u = *reinterpret_cast<const uint4*>(wB + r16 * 28 + slhi);
    bl0.u = *reinterpret_cast<const uint4*>(wB + r16 * 28 + sllo);
    bh1.u = *reinterpret_cast<const uint4*>(wB + (16 + r16) * 28 + slhi);
    bl1.u = *reinterpret_cast<const uint4*>(wB + (16 + r16) * 28 + sllo);
    const float b2_0 = sb2[r16],      b2_1 = sb2[16 + r16];
    const float w3_0 = sw3[r16],      w3_1 = sw3[16 + r16];
    const unsigned keepA = (g < 3) ? 0xffffffffu : 0u;   // frag regs 0,1
    const unsigned keepB = (g < 2) ? 0xffffffffu : 0u;   // frag regs 2,3

    // ---- 4 MFMA passes of 16 samples each ----
#pragma unroll
    for (int p = 0; p < 4; ++p) {
        const int rowA = w * 64 + p * 16 + r16;
        U4B ah, al;
        ah.u = *reinterpret_cast<const uint4*>(hs + rowA * 28 + slhi);
        al.u = *reinterpret_cast<const uint4*>(hs + rowA * 28 + sllo);
        ah.u.x &= keepA; ah.u.y &= keepA; ah.u.z &= keepB; ah.u.w &= keepB;
        al.u.x &= keepA; al.u.y &= keepA; al.u.z &= keepB; al.u.w &= keepB;

        f32x4 a0 = {0.f, 0.f, 0.f, 0.f}, a1 = {0.f, 0.f, 0.f, 0.f};
        a0 = __builtin_amdgcn_mfma_f32_16x16x32_bf16(ah.b, bl0.b, a0, 0, 0, 0);
        a0 = __builtin_amdgcn_mfma_f32_16x16x32_bf16(al.b, bh0.b, a0, 0, 0, 0);
        a0 = __builtin_amdgcn_mfma_f32_16x16x32_bf16(ah.b, bh0.b, a0, 0, 0, 0);
        a1 = __builtin_amdgcn_mfma_f32_16x16x32_bf16(ah.b, bl1.b, a1, 0, 0, 0);
        a1 = __builtin_amdgcn_mfma_f32_16x16x32_bf16(al.b, bh1.b, a1, 0, 0, 0);
        a1 = __builtin_amdgcn_mfma_f32_16x16x32_bf16(ah.b, bh1.b, a1, 0, 0, 0);

        // bias + relu + per-lane partials (cols >=20 are exactly 0)
#define EPI(r) \
        const float g0_##r = fmaxf(a0[r] + b2_0, 0.f); \
        const float g1_##r = fmaxf(a1[r] + b2_1, 0.f); \
        float S1_##r = g0_##r + g1_##r; \
        float S2_##r = fmaf(g0_##r, g0_##r, g1_##r * g1_##r); \
        float S3_##r = fmaf(g0_##r, w3_0, g1_##r * w3_1);
        EPI(0) EPI(1) EPI(2) EPI(3)
#undef EPI

        // 16-lane butterfly reductions (12 independent chains)
#define R16X(v) { v += __shfl_xor(v, 1); v += __shfl_xor(v, 2); \
                  v += __shfl_xor(v, 4); v += __shfl_xor(v, 8); }
        R16X(S1_0) R16X(S1_1) R16X(S1_2) R16X(S1_3)
        R16X(S2_0) R16X(S2_1) R16X(S2_2) R16X(S2_3)
        R16X(S3_0) R16X(S3_1) R16X(S3_2) R16X(S3_3)
#undef R16X

        // LN2 folded into layer-3: t = r2*S3 - r2*mu*w3sum + b3
#define TFIN(r) \
        const float mu_##r  = S1_##r * 0.05f; \
        const float var_##r = fmaf(-mu_##r, mu_##r, S2_##r * 0.05f); \
        const float rq_##r  = __builtin_amdgcn_rsqf(var_##r + 1e-5f); \
        const float t_##r   = fmaf(rq_##r, S3_##r, fmaf(-mu_##r * rq_##r, w3sum, bb3));
        TFIN(0) TFIN(1) TFIN(2) TFIN(3)
#undef TFIN

        if (r16 < 4) {   // lane (g, r16) stores sample 4g+r16 of this pass
            const float ts = (r16 == 0) ? t_0 : (r16 == 1) ? t_1
                           : (r16 == 2) ? t_2 : t_3;
            const int q = q0b + w * 64 + p * 16 + g * 4 + r16;
            tb[(((size_t)k * T_ + (q >> 7)) * N_ + n) * B_ + (q & 127)] = ts;
        }
    }
}

// ---------------------------------------------------------------------------
// Kernel 3: one WAVE per (k,t): standardize t over b (ddof=1, std+1e-8),
// in-lane product over n, partial = pj^2/2560 (product of 16 marginal means
// underflows to 0 in the fp32 reference; verified R2-R7). Plain stores.
// ---------------------------------------------------------------------------
__global__ __launch_bounds__(256) void k_fin(const float* __restrict__ tb,
                                             float* __restrict__ partials)
{
    const int gw = blockIdx.x * 4 + (threadIdx.x >> 6);   // 0..2559
    const int l  = threadIdx.x & 63;
    const float* __restrict__ base = tb + (size_t)gw * (N_ * B_);

#define DECLZ(n) float z0_##n = base[(n) * B_ + l], z1_##n = base[(n) * B_ + 64 + l];
    REP16(DECLZ)
#undef DECLZ

#define STDZ(n) { \
    const float mu = wsum(z0_##n + z1_##n) * (1.f / 128.f); \
    const float d0 = z0_##n - mu, d1 = z1_##n - mu; \
    const float vv = wsum(fmaf(d0, d0, d1 * d1)); \
    const float rr = 1.f / (sqrtf(vv * (1.f / 127.f)) + 1e-8f); \
    z0_##n = d0 * rr; z1_##n = d1 * rr; }
    REP16(STDZ)
#undef STDZ

    float p0 = 1.f, p1 = 1.f;
#define PRODZ(n) p0 *= z0_##n; p1 *= z1_##n;
    REP16(PRODZ)
#undef PRODZ
    const float pj = wsum(p0 + p1) * (1.f / 128.f);

    if (l == 0)
        partials[gw] = pj * pj * (1.f / (K_ * T_));
}

// ---------------------------------------------------------------------------
// Kernel 4: sum 2560 partials -> out. (Kernel-boundary coherence.)
// ---------------------------------------------------------------------------
__global__ __launch_bounds__(256) void k_sum(const float* __restrict__ partials,
                                             float* __restrict__ out)
{
    __shared__ double sred[4];
    const int tid = threadIdx.x;
    double a = 0.0;
#pragma unroll
    for (int j = 0; j < 10; ++j) a += (double)partials[j * 256 + tid];
#pragma unroll
    for (int off = 32; off; off >>= 1) a += __shfl_xor(a, off);
    if ((tid & 63) == 0) sred[tid >> 6] = a;
    __syncthreads();
    if (tid == 0) out[0] = (float)(sred[0] + sred[1] + sred[2] + sred[3]);
}

// ---------------------------------------------------------------------------
extern "C" void kernel_launch(void* const* d_in, const int* in_sizes, int n_in,
                              void* d_out, int out_size, void* d_ws, size_t ws_size,
                              hipStream_t stream)
{
    const float* x  = (const float*)d_in[0];
    const float* W1 = (const float*)d_in[1];
    const float* b1 = (const float*)d_in[2];
    const float* W2 = (const float*)d_in[3];
    const float* b2 = (const float*)d_in[4];
    const float* W3 = (const float*)d_in[5];
    const float* b3 = (const float*)d_in[6];
    float* out = (float*)d_out;

    char* ws = (char*)d_ws;
    float* xs2      = (float*)ws;                              // 2 MB [N][T][B]
    float* tb       = (float*)(ws + 2097152);                  // 20 MB [K][T][N][B]
    float* partials = (float*)(ws + 23068672);                 // 10 KB [2560]

    k_std<<<1024, 256, 0, stream>>>(x, xs2);

    dim3 g2(S_ / 256, K_ * N_);                                // 128 x 160
    k_mlp<<<g2, 256, 0, stream>>>(xs2, W1, b1, W2, b2, W3, b3, tb);

    k_fin<<<(K_ * T_) / 4, 256, 0, stream>>>(tb, partials);    // 640 blocks
    k_sum<<<1, 256, 0, stream>>>(partials, out);
}